// Round 6
// baseline (886.860 us; speedup 1.0000x reference)
//
#include <hip/hip_runtime.h>

typedef unsigned short u16;
typedef unsigned int u32;
typedef __attribute__((ext_vector_type(8))) short bf16x8;
typedef __attribute__((ext_vector_type(4))) float f32x4;

__device__ __forceinline__ u16 f2bf(float f) {
  u32 u = __float_as_uint(f);
  u += 0x7fffu + ((u >> 16) & 1u);
  return (u16)(u >> 16);
}
__device__ __forceinline__ float bf2f(short h) {
  return __uint_as_float(((u32)(u16)h) << 16);
}

// ---------------- convert x: f32 -> bf16 (straight) ----------------
__global__ __launch_bounds__(256) void k_cvt(const float* __restrict__ in, u16* __restrict__ out, int n) {
  int idx = (blockIdx.x * 256 + threadIdx.x) * 8;
  if (idx >= n) return;
  float4 a = *(const float4*)&in[idx];
  float4 b = *(const float4*)&in[idx + 4];
  union { u16 h[8]; uint4 v; } t;
  t.h[0] = f2bf(a.x); t.h[1] = f2bf(a.y); t.h[2] = f2bf(a.z); t.h[3] = f2bf(a.w);
  t.h[4] = f2bf(b.x); t.h[5] = f2bf(b.y); t.h[6] = f2bf(b.z); t.h[7] = f2bf(b.w);
  *(uint4*)&out[idx] = t.v;
}

// ---------------- transpose+convert: out[c][r] = bf16(in[r][c]) ----------------
__global__ __launch_bounds__(256) void k_tcvt(const float* __restrict__ in, u16* __restrict__ out, int R, int C) {
  __shared__ u16 T[64 * 72];
  int t = threadIdx.x;
  int r0 = blockIdx.y * 64, c0 = blockIdx.x * 64;
  for (int i = 0; i < 4; i++) {
    int cc = i * 256 + t; int r = cc >> 4; int s = cc & 15;
    float4 v = *(const float4*)&in[(size_t)(r0 + r) * C + c0 + s * 4];
    T[r * 72 + s * 4 + 0] = f2bf(v.x);
    T[r * 72 + s * 4 + 1] = f2bf(v.y);
    T[r * 72 + s * 4 + 2] = f2bf(v.z);
    T[r * 72 + s * 4 + 3] = f2bf(v.w);
  }
  __syncthreads();
  for (int i = 0; i < 2; i++) {
    int cc = i * 256 + t; int c = cc >> 3; int s2 = cc & 7;
    union { u16 h[8]; uint4 v; } tmp;
    for (int e = 0; e < 8; e++) tmp.h[e] = T[(s2 * 8 + e) * 72 + c];
    *(uint4*)&out[(size_t)(c0 + c) * R + r0 + s2 * 8] = tmp.v;
  }
}

// ---------------- transpose v-part of qkv into Vt[512][8192] ----------------
__global__ __launch_bounds__(256) void k_tv(const u16* __restrict__ qkv, u16* __restrict__ vt) {
  __shared__ u16 T[64 * 72];
  int t = threadIdx.x;
  int r0 = blockIdx.y * 64, d0 = blockIdx.x * 64;
  for (int i = 0; i < 2; i++) {
    int cc = i * 256 + t; int r = cc >> 3; int s = cc & 7;
    *(uint4*)&T[r * 72 + s * 8] = *(const uint4*)&qkv[(size_t)(r0 + r) * 1536 + 1024 + d0 + s * 8];
  }
  __syncthreads();
  for (int i = 0; i < 2; i++) {
    int cc = i * 256 + t; int d = cc >> 3; int s2 = cc & 7;
    union { u16 h[8]; uint4 v; } tmp;
    for (int e = 0; e < 8; e++) tmp.h[e] = T[(s2 * 8 + e) * 72 + d];
    *(uint4*)&vt[(size_t)(d0 + d) * 8192 + r0 + s2 * 8] = tmp.v;
  }
}

// ---------------- GEMM (m97 structure) ----------------
__global__ __launch_bounds__(256) void k_gemm(const u16* __restrict__ A, const u16* __restrict__ Bt,
                                              const float* __restrict__ bias,
                                              u16* __restrict__ Cb, float* __restrict__ Cf,
                                              int M, int N, int K) {
  __shared__ u16 As[128 * 64];
  __shared__ u16 Bs[128 * 64];
  const int t = threadIdx.x;
  const int l = t & 63, w = t >> 6;
  const int l16 = l & 15, g = l >> 4;
  const int m0 = blockIdx.y * 128, n0 = blockIdx.x * 128;
  const int wr = (w >> 1) * 64, wc = (w & 1) * 64;
  f32x4 acc[4][4] = {};
  for (int kk = 0; kk < K; kk += 64) {
    __syncthreads();
#pragma unroll
    for (int i = 0; i < 4; i++) {
      int c = i * 256 + t;
      int r = c >> 3, g2 = c & 7;
      int sg = g2 ^ (r & 7);
      __builtin_amdgcn_global_load_lds(
          (const __attribute__((address_space(1))) u32*)(A + (size_t)(m0 + r) * K + kk + sg * 8),
          (__attribute__((address_space(3))) u32*)&As[c * 8], 16, 0, 0);
      __builtin_amdgcn_global_load_lds(
          (const __attribute__((address_space(1))) u32*)(Bt + (size_t)(n0 + r) * K + kk + sg * 8),
          (__attribute__((address_space(3))) u32*)&Bs[c * 8], 16, 0, 0);
    }
    __syncthreads();
#pragma unroll
    for (int kh = 0; kh < 2; kh++) {
      bf16x8 a[4];
#pragma unroll
      for (int mi = 0; mi < 4; mi++) {
        int row = wr + 16 * mi + l16;
        int s = (kh * 4 + g) ^ (row & 7);
        a[mi] = *(const bf16x8*)&As[row * 64 + s * 8];
      }
#pragma unroll
      for (int ni = 0; ni < 4; ni++) {
        int row = wc + 16 * ni + l16;
        int s = (kh * 4 + g) ^ (row & 7);
        bf16x8 b = *(const bf16x8*)&Bs[row * 64 + s * 8];
#pragma unroll
        for (int mi = 0; mi < 4; mi++)
          acc[mi][ni] = __builtin_amdgcn_mfma_f32_16x16x32_bf16(a[mi], b, acc[mi][ni], 0, 0, 0);
      }
    }
  }
#pragma unroll
  for (int ni = 0; ni < 4; ni++) {
    int col = n0 + wc + 16 * ni + l16;
    float bv = bias[col];
#pragma unroll
    for (int mi = 0; mi < 4; mi++) {
      int row0 = m0 + wr + 16 * mi + 4 * g;
#pragma unroll
      for (int r = 0; r < 4; r++) {
        float v = acc[mi][ni][r] + bv;
        if (Cf) Cf[(size_t)(row0 + r) * N + col] = v;
        else    Cb[(size_t)(row0 + r) * N + col] = f2bf(v);
      }
    }
  }
}

// ---------------- flash v6: BQ=256, 8 waves x (32q rows, full 512d), 32-tok KV tiles ----------------
// Chunk = 16 tiles (512 tok). Exactly 256 16-step blocks (f<256, long-first) + 16 8-step tails.
// 16-step block f: qb = max qb with qb*qb/4 <= f, c = f - qb*qb/4. Tail f>=256: qb=2(f-256), c=qb/2.
// slot(qb,c) = qb + (qb-1)^2/4 + c (qb>=1), c for qb=0 -> slot 0. Partials: 256KB/slot, 3 regions.
__global__ __launch_bounds__(512, 1) void k_flash6(const u16* __restrict__ qkv, const u16* __restrict__ vt,
                                                   u16* __restrict__ opA, u16* __restrict__ opB,
                                                   u16* __restrict__ opC, float* __restrict__ ml) {
  __shared__ u16 Ks[2][32 * 512];   // [kv][d], 16B units XOR-swizzled (unit^ (row&7)) as v5
  __shared__ u16 Vs[2][32 * 512];   // subtiled: unit U = (d>>4)*64 + (kv>>3)*16 + (d&15)
  __shared__ u16 Ps[8][2][16 * 40]; // per-wave, per-q-block P strip [16 q][32 kv], stride 40
  int f = blockIdx.x;
  int qb, c;
  if (f < 256) {
    qb = 31;
    while (((qb * qb) >> 2) > f) --qb;
    c = f - ((qb * qb) >> 2);
  } else {
    qb = 2 * (f - 256);
    c = qb >> 1;
  }
  const int slot = (qb ? qb + (((qb - 1) * (qb - 1)) >> 2) : 0) + c;
  const int jlo = c * 16;
  const int jhi = min(jlo + 16, 8 * (qb + 1));
  const int t = threadIdx.x;
  const int l = t & 63, w = t >> 6;
  const int l16 = l & 15, g = l >> 4;
  const int q0 = qb * 256;
  const int wq = q0 + 32 * w;                 // wave's first q row
  const float scale = 0.044194173824159216f;  // 1/sqrt(512)

  auto stageK = [&](int jt, int buf) {
    const u16* src = qkv + (size_t)(jt * 32) * 1536 + 512;
#pragma unroll
    for (int i = 0; i < 4; i++) {
      int cc = i * 512 + t;                   // 16B unit 0..2047
      int r = cc >> 6, u = cc & 63;
      int su = (u & 56) | ((u & 7) ^ (r & 7));
      __builtin_amdgcn_global_load_lds(
          (const __attribute__((address_space(1))) u32*)(src + (size_t)r * 1536 + su * 8),
          (__attribute__((address_space(3))) u32*)&Ks[buf][cc * 8], 16, 0, 0);
    }
  };
  auto stageV = [&](int jt, int buf) {
    const int tok0 = jt * 32;
#pragma unroll
    for (int i = 0; i < 4; i++) {
      int cc = i * 512 + t;                   // unit U: tile=U>>6, u=(U>>4)&3, dl=U&15
      int tile = cc >> 6, u = (cc >> 4) & 3, dl = cc & 15;
      int d = tile * 16 + dl;
      __builtin_amdgcn_global_load_lds(
          (const __attribute__((address_space(1))) u32*)(vt + (size_t)d * 8192 + tok0 + u * 8),
          (__attribute__((address_space(3))) u32*)&Vs[buf][cc * 8], 16, 0, 0);
    }
  };

  // hoist Q: 2 q-blocks x 16 k-slices (128 VGPR)
  bf16x8 qa0[16], qa1[16];
#pragma unroll
  for (int ks = 0; ks < 16; ks++) {
    qa0[ks] = *(const bf16x8*)&qkv[(size_t)(wq + l16) * 1536 + ks * 32 + g * 8];
    qa1[ks] = *(const bf16x8*)&qkv[(size_t)(wq + 16 + l16) * 1536 + ks * 32 + g * 8];
  }

  f32x4 acc0[32] = {}, acc1[32] = {};         // O rows 16qh+4g+r, col 16db+l16
  float m0s[4], l0s[4], m1s[4], l1s[4];
#pragma unroll
  for (int r = 0; r < 4; r++) { m0s[r] = -1.0e30f; l0s[r] = 0.f; m1s[r] = -1.0e30f; l1s[r] = 0.f; }

  stageK(jlo, jlo & 1);
  stageV(jlo, jlo & 1);
  __syncthreads();

  for (int jt = jlo; jt < jhi; ++jt) {
    const int buf = jt & 1;
    const int tok0 = jt * 32;
    if (jt + 1 < jhi) { stageK(jt + 1, buf ^ 1); stageV(jt + 1, buf ^ 1); }

    // ---- QK^T: 32 rows x 32 cols per wave, K=512; B-frags shared by 2 q-blocks ----
    f32x4 S00 = {0.f,0.f,0.f,0.f}, S01 = {0.f,0.f,0.f,0.f};
    f32x4 S10 = {0.f,0.f,0.f,0.f}, S11 = {0.f,0.f,0.f,0.f};
#pragma unroll
    for (int ks = 0; ks < 16; ks++) {
      int u = 4 * ks + g;
      int su = (u & 56) | ((u & 7) ^ (l16 & 7));
      bf16x8 k0 = *(const bf16x8*)&Ks[buf][l16 * 512 + su * 8];
      bf16x8 k1 = *(const bf16x8*)&Ks[buf][(16 + l16) * 512 + su * 8];
      S00 = __builtin_amdgcn_mfma_f32_16x16x32_bf16(qa0[ks], k0, S00, 0, 0, 0);
      S01 = __builtin_amdgcn_mfma_f32_16x16x32_bf16(qa0[ks], k1, S01, 0, 0, 0);
      S10 = __builtin_amdgcn_mfma_f32_16x16x32_bf16(qa1[ks], k0, S10, 0, 0, 0);
      S11 = __builtin_amdgcn_mfma_f32_16x16x32_bf16(qa1[ks], k1, S11, 0, 0, 0);
    }
    // ---- scale + causal mask ----
#pragma unroll
    for (int r = 0; r < 4; r++) { S00[r] *= scale; S01[r] *= scale; S10[r] *= scale; S11[r] *= scale; }
    if (tok0 + 31 > wq) {
      const int km0 = tok0 + l16, km1 = tok0 + 16 + l16;
      const int qp0 = wq + 4 * g, qp1 = wq + 16 + 4 * g;
#pragma unroll
      for (int r = 0; r < 4; r++) {
        if (km0 > qp0 + r) S00[r] = -1e10f;
        if (km1 > qp0 + r) S01[r] = -1e10f;
        if (km0 > qp1 + r) S10[r] = -1e10f;
        if (km1 > qp1 + r) S11[r] = -1e10f;
      }
    }
    // ---- wave-local online softmax, defer-max THR=6, both q-blocks ----
    float pm0[4], pm1[4];
#pragma unroll
    for (int r = 0; r < 4; r++) {
      float v0 = fmaxf(S00[r], S01[r]);
      float v1 = fmaxf(S10[r], S11[r]);
#pragma unroll
      for (int off = 1; off < 16; off <<= 1) {
        v0 = fmaxf(v0, __shfl_xor(v0, off));
        v1 = fmaxf(v1, __shfl_xor(v1, off));
      }
      pm0[r] = v0; pm1[r] = v1;
    }
    float sc0[4] = {1.f,1.f,1.f,1.f}, sc1[4] = {1.f,1.f,1.f,1.f};
    int need = 0;
#pragma unroll
    for (int r = 0; r < 4; r++)
      need |= (pm0[r] > m0s[r] + 6.f) | (pm1[r] > m1s[r] + 6.f);
    if (__any(need)) {
#pragma unroll
      for (int r = 0; r < 4; r++) {
        float mn0 = fmaxf(m0s[r], pm0[r]);
        float mn1 = fmaxf(m1s[r], pm1[r]);
        sc0[r] = __expf(m0s[r] - mn0); m0s[r] = mn0;
        sc1[r] = __expf(m1s[r] - mn1); m1s[r] = mn1;
      }
#pragma unroll
      for (int db = 0; db < 32; db++)
#pragma unroll
        for (int r = 0; r < 4; r++) { acc0[db][r] *= sc0[r]; acc1[db][r] *= sc1[r]; }
    }
#pragma unroll
    for (int r = 0; r < 4; r++) {
      float p00 = __expf(S00[r] - m0s[r]);
      float p01 = __expf(S01[r] - m0s[r]);
      float p10 = __expf(S10[r] - m1s[r]);
      float p11 = __expf(S11[r] - m1s[r]);
      Ps[w][0][(4 * g + r) * 40 + l16] = f2bf(p00);
      Ps[w][0][(4 * g + r) * 40 + 16 + l16] = f2bf(p01);
      Ps[w][1][(4 * g + r) * 40 + l16] = f2bf(p10);
      Ps[w][1][(4 * g + r) * 40 + 16 + l16] = f2bf(p11);
      float s0 = p00 + p01, s1 = p10 + p11;
#pragma unroll
      for (int off = 1; off < 16; off <<= 1) {
        s0 += __shfl_xor(s0, off);
        s1 += __shfl_xor(s1, off);
      }
      l0s[r] = l0s[r] * sc0[r] + s0;
      l1s[r] = l1s[r] * sc1[r] + s1;
    }
    // ---- PV: O[32x512] += P[32x32] @ V[32x512]; V-frags shared by 2 q-blocks ----
    bf16x8 pa0 = *(const bf16x8*)&Ps[w][0][l16 * 40 + g * 8];
    bf16x8 pa1 = *(const bf16x8*)&Ps[w][1][l16 * 40 + g * 8];
#pragma unroll
    for (int db = 0; db < 32; db++) {
      bf16x8 vb = *(const bf16x8*)&Vs[buf][db * 512 + g * 128 + l16 * 8];
      acc0[db] = __builtin_amdgcn_mfma_f32_16x16x32_bf16(pa0, vb, acc0[db], 0, 0, 0);
      acc1[db] = __builtin_amdgcn_mfma_f32_16x16x32_bf16(pa1, vb, acc1[db], 0, 0, 0);
    }
    __syncthreads();   // drains vmcnt (prefetch done) + protects dbuf
  }

  // ---- epilogue: vectorized unnormalized partials + (m,l) ----
  u16* op = slot < 76 ? opA + (size_t)slot * 131072
          : slot < 154 ? opB + (size_t)(slot - 76) * 131072
          : opC + (size_t)(slot - 154) * 131072;
  uint4* opw = (uint4*)op;
#pragma unroll
  for (int db2 = 0; db2 < 16; db2++) {
    union { u16 h[8]; uint4 v; } p0, p1;
#pragma unroll
    for (int j = 0; j < 8; j++) {
      p0.h[j] = f2bf(acc0[2 * db2 + (j >> 2)][j & 3]);
      p1.h[j] = f2bf(acc1[2 * db2 + (j >> 2)][j & 3]);
    }
    opw[((2 * w + 0) * 16 + db2) * 64 + l] = p0.v;
    opw[((2 * w + 1) * 16 + db2) * 64 + l] = p1.v;
  }
  if (l16 == 0) {
#pragma unroll
    for (int r = 0; r < 4; r++) {
      int r0 = 32 * w + 4 * g + r;
      ml[slot * 512 + r0 * 2 + 0] = m0s[r];
      ml[slot * 512 + r0 * 2 + 1] = l0s[r];
      int r1 = r0 + 16;
      ml[slot * 512 + r1 * 2 + 0] = m1s[r];
      ml[slot * 512 + r1 * 2 + 1] = l1s[r];
    }
  }
}

// ---------------- combine partials -> normalized O (bf16) ----------------
__global__ __launch_bounds__(512) void k_comb4(const u16* __restrict__ opA, const u16* __restrict__ opB,
                                               const u16* __restrict__ opC, const float* __restrict__ ml,
                                               u16* __restrict__ Ob) {
  __shared__ float wgtS[16][256];
  const int qb = blockIdx.y, ds = blockIdx.x;
  const int nch = (qb + 2) >> 1;
  const int base = qb ? qb + (((qb - 1) * (qb - 1)) >> 2) : 0;
  const int t = threadIdx.x;
  if (t < 256) {
    float M = -3.0e38f;
    for (int c2 = 0; c2 < nch; c2++) M = fmaxf(M, ml[(base + c2) * 512 + t * 2]);
    float L = 0.f;
    for (int c2 = 0; c2 < nch; c2++)
      L += __expf(ml[(base + c2) * 512 + t * 2] - M) * ml[(base + c2) * 512 + t * 2 + 1];
    float inv = 1.0f / L;
    for (int c2 = 0; c2 < nch; c2++)
      wgtS[c2][t] = __expf(ml[(base + c2) * 512 + t * 2] - M) * inv;
  }
  __syncthreads();
#pragma unroll
  for (int uu = 0; uu < 4; uu++) {
    int e = uu * 512 + t;
    int qh = e >> 7, db2p = (e >> 6) & 1, l = e & 63;
    int db2 = ds * 2 + db2p;
    int idx = (qh * 16 + db2) * 64 + l;
    int rbase = qh * 16 + 4 * (l >> 4);
    float o[8] = {};
    for (int c2 = 0; c2 < nch; c2++) {
      int slot = base + c2;
      const uint4* src = slot < 76 ? (const uint4*)(opA + (size_t)slot * 131072)
                       : slot < 154 ? (const uint4*)(opB + (size_t)(slot - 76) * 131072)
                       : (const uint4*)(opC + (size_t)(slot - 154) * 131072);
      uint4 v = src[idx];
      union { uint4 u; u16 h[8]; } un; un.u = v;
#pragma unroll
      for (int j = 0; j < 8; j++) o[j] += wgtS[c2][rbase + (j & 3)] * bf2f(un.h[j]);
    }
#pragma unroll
    for (int j = 0; j < 8; j++) {
      int row = qb * 256 + rbase + (j & 3);
      int col = 32 * db2 + 16 * (j >> 2) + (l & 15);
      Ob[(size_t)row * 512 + col] = f2bf(o[j]);
    }
  }
}

extern "C" void kernel_launch(void* const* d_in, const int* in_sizes, int n_in,
                              void* d_out, int out_size, void* d_ws, size_t ws_size,
                              hipStream_t stream) {
  const float* x     = (const float*)d_in[0];
  const float* w_qkv = (const float*)d_in[1];
  const float* b_qkv = (const float*)d_in[2];
  const float* w_out = (const float*)d_in[3];
  const float* b_out = (const float*)d_in[4];
  float* out = (float*)d_out;
  char* ws = (char*)d_ws;
  // base layout
  u16* xb    = (u16*)(ws);               // [8192][1024] bf16 (dead after gemm1 -> opA)
  u16* wqkvT = (u16*)(ws + 16777216);    // [1536][1024] bf16 (dead after gemm1 -> opA)
  u16* woutT = (u16*)(ws + 19922944);    // [1024][512]  bf16
  u16* qkv   = (u16*)(ws + 20971520);    // [8192][1536] bf16
  u16* vt    = (u16*)(ws + 46137344);    // [512][8192]  bf16
  u16* Ob    = (u16*)(ws + 54525952);    // [8192][512]  bf16 (ends 62914560)

  // partial O slots: 272 x 256KB. A: [0,19922944) = 76 slots (xb+wqkvT, dead);
  // B: [62914560, 83361792) = 78 slots; C: d_out (33.5 MB scratch until final GEMM) = 118+ slots.
  u16* opA = (u16*)ws;
  u16* opB = (u16*)(ws + 62914560);
  u16* opC = (u16*)d_out;
  float* mlp = (float*)(ws + 83361792);  // 272*512*4 = 557056 -> ends 83918848

  k_cvt<<<4096, 256, 0, stream>>>(x, xb, 8192 * 1024);
  k_tcvt<<<dim3(24, 16), 256, 0, stream>>>(w_qkv, wqkvT, 1024, 1536);
  k_tcvt<<<dim3(16, 8), 256, 0, stream>>>(w_out, woutT, 512, 1024);
  k_gemm<<<dim3(12, 64), 256, 0, stream>>>(xb, wqkvT, b_qkv, qkv, nullptr, 8192, 1536, 1024);
  k_tv<<<dim3(8, 128), 256, 0, stream>>>(qkv, vt);
  k_flash6<<<272, 512, 0, stream>>>(qkv, vt, opA, opB, opC, mlp);
  k_comb4<<<dim3(8, 32), 512, 0, stream>>>(opA, opB, opC, mlp, Ob);
  k_gemm<<<dim3(8, 64), 256, 0, stream>>>(Ob, woutT, b_out, nullptr, out, 8192, 1024, 512);
}